// Round 3
// baseline (644.024 us; speedup 1.0000x reference)
//
#include <hip/hip_runtime.h>
#include <stdint.h>

typedef unsigned int       u32;
typedef unsigned long long u64;
typedef unsigned short     u16;

typedef float f32x4 __attribute__((ext_vector_type(4)));
typedef short s16x8 __attribute__((ext_vector_type(8)));

#define AS1 __attribute__((address_space(1)))
#define AS3 __attribute__((address_space(3)))

constexpr int BATCH = 8, SEQ = 2048, DIM = 512, CODES = 8192;
constexpr int MROWS = BATCH * SEQ;          // 16384
constexpr int CAP   = 128;                  // candidate slots per row
#define MARGIN          1.0f                // append margin (>=13 sigma of bf16 dot err)
#define RESCORE_MARGIN  0.6f                // exact-rescore filter (~8 sigma)

// ---- ordered-uint encode for float min ----
__device__ __forceinline__ u32 encf(float f) {
    u32 u = __float_as_uint(f);
    return (u & 0x80000000u) ? ~u : (u | 0x80000000u);
}
__device__ __forceinline__ u16 f2bf(float f) {           // RTNE, finite inputs
    u32 u = __float_as_uint(f);
    return (u16)((u + 0x7fffu + ((u >> 16) & 1u)) >> 16);
}

// ---------------- pass 0: fused fp32->bf16 cast + numpy-pairwise-exact row sumsq ----------------
// 64 rows/block, 4 col-panels of 128 staged through LDS (coalesced float4 global reads).
// Sum order replicates numpy pairwise_sum(512): 4 base-128 blocks of 8 accumulators,
// ((r0+r1)+(r2+r3))+((r4+r5)+(r6+r7)) per block, combined (b0+b1)+(b2+b3).
__global__ __launch_bounds__(256) void k_prep(const float* __restrict__ src,
                                              u16* __restrict__ dst,
                                              float* __restrict__ dsq,
                                              u32* __restrict__ cnt, int zn) {
#pragma clang fp contract(off)
    __shared__ float lp[64 * 133];
    const int t = threadIdx.x;
    const int row0 = blockIdx.x * 64;
    const int gid = blockIdx.x * 256 + t;
    if (gid < zn) cnt[gid] = 0u;

    float blk[4];
    for (int p = 0; p < 4; p++) {
#pragma unroll
        for (int k = 0; k < 8; k++) {
            int idx = t + 256 * k;
            int row = idx >> 5, c4 = idx & 31;
            const float* gp = src + (size_t)(row0 + row) * DIM + p * 128 + c4 * 4;
            float4 v = *(const float4*)gp;
            u16 o[4] = {f2bf(v.x), f2bf(v.y), f2bf(v.z), f2bf(v.w)};
            *(u64*)(dst + (size_t)(row0 + row) * DIM + p * 128 + c4 * 4) = *(u64*)o;
            int la = row * 133 + c4 * 4;
            lp[la] = v.x; lp[la + 1] = v.y; lp[la + 2] = v.z; lp[la + 3] = v.w;
        }
        __syncthreads();
        if (t < 64) {
            const float* q = lp + t * 133;
            float a0 = q[0]*q[0], a1 = q[1]*q[1], a2 = q[2]*q[2], a3 = q[3]*q[3];
            float a4 = q[4]*q[4], a5 = q[5]*q[5], a6 = q[6]*q[6], a7 = q[7]*q[7];
            for (int i = 1; i < 16; i++) {
                const float* r = q + i * 8;
                a0 = a0 + r[0]*r[0]; a1 = a1 + r[1]*r[1];
                a2 = a2 + r[2]*r[2]; a3 = a3 + r[3]*r[3];
                a4 = a4 + r[4]*r[4]; a5 = a5 + r[5]*r[5];
                a6 = a6 + r[6]*r[6]; a7 = a7 + r[7]*r[7];
            }
            blk[p] = ((a0 + a1) + (a2 + a3)) + ((a4 + a5) + (a6 + a7));
        }
        __syncthreads();
    }
    if (t < 64) dsq[row0 + t] = (blk[0] + blk[1]) + (blk[2] + blk[3]);
}

// ---------------- pass 1: bf16 MFMA GEMM + per-tile LDS-reduced min + margin-append ----------------
// grid = 2048: blockIdx -> rowTile (bx>>4) x colChunk (bx&15, 512 cols each)
// Staging uses the XOR-16B-chunk swizzle (r1 fix, conflict-free).
// Epilogue v3: per-lane 4-col mins -> LDS scratch (aliases staging LDS) ->
// 128 row-owner threads publish thr[row] -> all lanes margin-append. No shfl
// chains, no LDS atomics, deterministic thresholds.
__global__ __launch_bounds__(256) void k_vq(const u16* __restrict__ A,   // [16384,512] bf16
                                            const u16* __restrict__ B,   // [8192,512] bf16
                                            const float* __restrict__ c2,
                                            u32* __restrict__ cnt,
                                            uint2* __restrict__ cand) {
    __shared__ u16 lAB[2 * 128 * 64];       // A tile | B tile (32 KiB)
    __shared__ float runm[128];
    __shared__ float thr[128];
    float* lmin = (float*)lAB;              // epilogue scratch 128*33 floats (16.9 KiB, aliased)

    const int t    = threadIdx.x;
    const int wave = t >> 6, lane = t & 63;
    const int lr   = lane & 15, quad = lane >> 4;
    const int bx   = blockIdx.x;
    const int row0 = (bx >> 4) * 128;
    const int col0 = (bx & 15) * 512;
    const int wRow = (wave >> 1) * 64;
    const int wCol = (wave & 1) * 64;
    const int s0   = (quad ^ (lr & 7)) * 8;   // swizzled u16 chunk offset, kk=0
    const int w16  = (wave & 1) * 16 + (lr ^ quad);   // scratch slot (bank-spread)

    if (t < 128) runm[t] = 3.4028235e38f;

    for (int ct = 0; ct < 4; ct++) {
        const int colBase = col0 + ct * 128;
        f32x4 acc[4][4];
#pragma unroll
        for (int i = 0; i < 4; i++)
#pragma unroll
            for (int j = 0; j < 4; j++) { f32x4 z = {0.f, 0.f, 0.f, 0.f}; acc[i][j] = z; }

        for (int kb = 0; kb < DIM; kb += 64) {
#pragma unroll
            for (int p = 0; p < 4; p++) {
                int off = t * 16 + p * 4096;            // byte offset in 16 KiB tile
                int rr  = off >> 7;                     // tile row (128 B/row)
                int cc  = (off >> 4) & 7;               // LDS chunk position
                int sc  = (cc ^ (rr & 7)) << 3;         // source u16 col (XOR swizzle)
                const u16* ga = A + (size_t)(row0 + rr) * DIM + kb + sc;
                const u16* gb = B + (size_t)(colBase + rr) * DIM + kb + sc;
                __builtin_amdgcn_global_load_lds((const AS1 u32*)ga,
                                                 (AS3 u32*)((char*)lAB + off), 16, 0, 0);
                __builtin_amdgcn_global_load_lds((const AS1 u32*)gb,
                                                 (AS3 u32*)((char*)lAB + 16384 + off), 16, 0, 0);
            }
            __syncthreads();
#pragma unroll
            for (int kk = 0; kk < 2; kk++) {
                const int soff = s0 ^ (kk * 32);        // (chunk ^ 4kk)*8 in u16
                s16x8 af[4], bf[4];
#pragma unroll
                for (int i = 0; i < 4; i++)
                    af[i] = *(const s16x8*)&lAB[(wRow + i * 16 + lr) * 64 + soff];
#pragma unroll
                for (int j = 0; j < 4; j++)
                    bf[j] = *(const s16x8*)&lAB[8192 + (wCol + j * 16 + lr) * 64 + soff];
#pragma unroll
                for (int i = 0; i < 4; i++)
#pragma unroll
                    for (int j = 0; j < 4; j++)
                        acc[i][j] = __builtin_amdgcn_mfma_f32_16x16x32_bf16(af[i], bf[j], acc[i][j], 0, 0, 0);
            }
            __syncthreads();
        }

        float c2v[4];
#pragma unroll
        for (int j = 0; j < 4; j++) c2v[j] = c2[colBase + wCol + j * 16 + lr];

        // phase 1: per-lane min over its 4 cols, per row -> scratch
#pragma unroll
        for (int i = 0; i < 4; i++) {
#pragma unroll
            for (int r = 0; r < 4; r++) {
                float v0 = c2v[0] - 2.0f * acc[i][0][r];
                float v1 = c2v[1] - 2.0f * acc[i][1][r];
                float v2 = c2v[2] - 2.0f * acc[i][2][r];
                float v3 = c2v[3] - 2.0f * acc[i][3][r];
                float mn = fminf(fminf(v0, v1), fminf(v2, v3));
                lmin[(wRow + i * 16 + quad * 4 + r) * 33 + w16] = mn;
            }
        }
        __syncthreads();
        // phase 2: row owners reduce 32 slots, update running min, publish threshold
        if (t < 128) {
            const float* q = lmin + t * 33;
            float mm = q[0];
#pragma unroll
            for (int k = 1; k < 32; k++) mm = fminf(mm, q[k]);
            float runv = fminf(runm[t], mm);
            runm[t] = runv;
            thr[t] = runv + MARGIN;
        }
        __syncthreads();
        // phase 3: margin-append (rare, divergent)
#pragma unroll
        for (int i = 0; i < 4; i++) {
#pragma unroll
            for (int r = 0; r < 4; r++) {
                const int lrow = wRow + i * 16 + quad * 4 + r;
                float th = thr[lrow];
                const int grow = row0 + lrow;
#pragma unroll
                for (int j = 0; j < 4; j++) {
                    float s = c2v[j] - 2.0f * acc[i][j][r];
                    if (s < th) {
                        u32 idx = atomicAdd(&cnt[grow], 1u);
                        if (idx < CAP)
                            cand[(size_t)grow * CAP + idx] =
                                make_uint2(__float_as_uint(s), (u32)(colBase + wCol + j * 16 + lr));
                    }
                }
            }
        }
    }
}

// ---------------- pass 2: exact rescore (fp64 dot, np-fp32 pipeline) + gather + PE ----------------
__global__ __launch_bounds__(256) void k_fin(const float* __restrict__ x,
                                             const float* __restrict__ cb,
                                             const float* __restrict__ c2,
                                             const float* __restrict__ x2,
                                             const u32* __restrict__ cnt,
                                             const uint2* __restrict__ cand,
                                             float* __restrict__ out) {
    const int row  = (blockIdx.x * 256 + threadIdx.x) >> 6;   // one wave per row
    const int lane = threadIdx.x & 63;
    int n = (int)cnt[row];
    if (n > CAP) n = CAP;
    const uint2* cd = cand + (size_t)row * CAP;

    float m = 3.4028235e38f;
    for (int i = lane; i < n; i += 64) m = fminf(m, __uint_as_float(cd[i].x));
#pragma unroll
    for (int mask = 32; mask; mask >>= 1) m = fminf(m, __shfl_xor(m, mask));
    const float thr = m + RESCORE_MARGIN;

    const float* xr = x + (size_t)row * DIM + lane * 8;
    float4 xv0 = *(const float4*)xr;
    float4 xv1 = *(const float4*)(xr + 4);
    const float x2v = x2[row];

    u64 best = ~0ull;
    for (int i = 0; i < n; i++) {
        uint2 e = cd[i];
        float sa = __uint_as_float(e.x);
        if (sa <= thr) {                                       // wave-uniform branch
            const float* cr = cb + (size_t)e.y * DIM + lane * 8;
            float4 c0 = *(const float4*)cr;
            float4 c1 = *(const float4*)(cr + 4);
            double d = (double)xv0.x * c0.x + (double)xv0.y * c0.y +
                       (double)xv0.z * c0.z + (double)xv0.w * c0.w +
                       (double)xv1.x * c1.x + (double)xv1.y * c1.y +
                       (double)xv1.z * c1.z + (double)xv1.w * c1.w;
#pragma unroll
            for (int mask = 32; mask; mask >>= 1) d += __shfl_xor(d, mask);
            float dot = (float)d;
            float s32 = (x2v - 2.0f * dot) + c2[e.y];          // np fp32 pipeline
            u64 key = ((u64)encf(s32) << 32) | (u64)e.y;       // lowest-index tie-break
            best = best < key ? best : key;
        }
    }
    u32 wcol = (u32)(best & 0xffffffffu);
    if (wcol >= (u32)CODES) wcol = 0;                          // unreachable safety

    const float* cw = cb + (size_t)wcol * DIM + lane * 8;
    float4 q0 = *(const float4*)cw;
    float4 q1 = *(const float4*)(cw + 4);
    const int spos = row & (SEQ - 1);
    float pe[8];
#pragma unroll
    for (int ii = 0; ii < 4; ii++) {
        int ipair = lane * 4 + ii;
        float dt  = expf((float)(2 * ipair) * (-0.017988946039035083f)); // ln(1e4)/512
        float ang = (float)spos * dt;
        float sv, cv;
        sincosf(ang, &sv, &cv);
        pe[2 * ii]     = sv;
        pe[2 * ii + 1] = cv;
    }
    float4* op = (float4*)(out + (size_t)row * DIM + lane * 8);
    op[0] = make_float4(q0.x + pe[0], q0.y + pe[1], q0.z + pe[2], q0.w + pe[3]);
    op[1] = make_float4(q1.x + pe[4], q1.y + pe[5], q1.z + pe[6], q1.w + pe[7]);
}

extern "C" void kernel_launch(void* const* d_in, const int* in_sizes, int n_in,
                              void* d_out, int out_size, void* d_ws, size_t ws_size,
                              hipStream_t stream) {
    const float* x  = (const float*)d_in[0];   // [8,2048,512]
    const float* cb = (const float*)d_in[1];   // [8192,512]
    float* out = (float*)d_out;

    char* ws = (char*)d_ws;
    u16*   Abf  = (u16*)ws;                                   // 16 MiB
    u16*   Bbf  = (u16*)(ws + 16777216);                      //  8 MiB
    float* c2   = (float*)(ws + 16777216 + 8388608);          // 32 KiB
    float* x2   = (float*)(ws + 16777216 + 8388608 + 32768);  // 64 KiB
    u32*   cnt  = (u32*)(ws + 16777216 + 8388608 + 32768 + 65536);            // 64 KiB
    uint2* cand = (uint2*)(ws + 16777216 + 8388608 + 32768 + 65536 + 65536);  // 16 MiB

    k_prep<<<dim3(256), dim3(256), 0, stream>>>(x, Abf, x2, cnt, MROWS);
    k_prep<<<dim3(128), dim3(256), 0, stream>>>(cb, Bbf, c2, cnt, 0);
    k_vq<<<dim3(2048), dim3(256), 0, stream>>>(Abf, Bbf, c2, cnt, cand);
    k_fin<<<dim3(4096), dim3(256), 0, stream>>>(x, cb, c2, x2, cnt, cand, out);
}

// Round 5
// 509.714 us; speedup vs baseline: 1.2635x; 1.2635x over previous
//
#include <hip/hip_runtime.h>
#include <stdint.h>

typedef unsigned int       u32;
typedef unsigned long long u64;
typedef unsigned short     u16;

typedef float f32x4 __attribute__((ext_vector_type(4)));
typedef short s16x8 __attribute__((ext_vector_type(8)));

#define AS1 __attribute__((address_space(1)))
#define AS3 __attribute__((address_space(3)))

constexpr int BATCH = 8, SEQ = 2048, DIM = 512, CODES = 8192;
constexpr int MROWS = BATCH * SEQ;          // 16384
constexpr int CAP   = 128;                  // candidate slots per row
#define MARGIN          1.0f                // append margin; stale-thr proof needs > 2*err_bf16 (~16 sigma here)
#define RESCORE_MARGIN  0.6f                // exact-rescore filter (~8 sigma)

// ---- ordered-uint encode for float min ----
__device__ __forceinline__ u32 encf(float f) {
    u32 u = __float_as_uint(f);
    return (u & 0x80000000u) ? ~u : (u | 0x80000000u);
}
__device__ __forceinline__ float decf(u32 e) {
    return (e & 0x80000000u) ? __uint_as_float(e & 0x7fffffffu) : __uint_as_float(~e);
}
__device__ __forceinline__ u16 f2bf(float f) {           // RTNE, finite inputs
    u32 u = __float_as_uint(f);
    return (u16)((u + 0x7fffu + ((u >> 16) & 1u)) >> 16);
}

// ---------------- pass 0: fused fp32->bf16 cast + numpy-pairwise-exact row sumsq ----------------
// One launch: blocks 0..255 handle x, 256..383 handle codebook; also zeroes cnt.
// Sum order replicates numpy pairwise_sum(512): 4 base-128 blocks of 8 accumulators,
// ((a0+a1)+(a2+a3))+((a4+a5)+(a6+a7)) per block, combined (b0+b1)+(b2+b3).
__global__ __launch_bounds__(256) void k_prep(const float* __restrict__ x,
                                              const float* __restrict__ cb,
                                              u16* __restrict__ dx,
                                              u16* __restrict__ dcb,
                                              float* __restrict__ x2,
                                              float* __restrict__ c2,
                                              u32* __restrict__ cnt) {
#pragma clang fp contract(off)
    __shared__ float lp[64 * 133];
    const int t  = threadIdx.x;
    const int bx = blockIdx.x;
    const int gid = bx * 256 + t;
    if (gid < MROWS) cnt[gid] = 0u;

    const float* src; u16* dst; float* dsq; int row0;
    if (bx < 256) { src = x;  dst = dx;  dsq = x2; row0 = bx * 64; }
    else          { src = cb; dst = dcb; dsq = c2; row0 = (bx - 256) * 64; }

    float blk[4];
    for (int p = 0; p < 4; p++) {
#pragma unroll
        for (int k = 0; k < 8; k++) {
            int idx = t + 256 * k;
            int row = idx >> 5, c4 = idx & 31;
            const float* gp = src + (size_t)(row0 + row) * DIM + p * 128 + c4 * 4;
            float4 v = *(const float4*)gp;
            u64 pk = (u64)f2bf(v.x) | ((u64)f2bf(v.y) << 16) |
                     ((u64)f2bf(v.z) << 32) | ((u64)f2bf(v.w) << 48);
            *(u64*)(dst + (size_t)(row0 + row) * DIM + p * 128 + c4 * 4) = pk;  // 8B-aligned
            int la = row * 133 + c4 * 4;
            lp[la] = v.x; lp[la + 1] = v.y; lp[la + 2] = v.z; lp[la + 3] = v.w;
        }
        __syncthreads();
        if (t < 64) {
            const float* q = lp + t * 133;
            float a0 = q[0]*q[0], a1 = q[1]*q[1], a2 = q[2]*q[2], a3 = q[3]*q[3];
            float a4 = q[4]*q[4], a5 = q[5]*q[5], a6 = q[6]*q[6], a7 = q[7]*q[7];
            for (int i = 1; i < 16; i++) {
                const float* r = q + i * 8;
                a0 = a0 + r[0]*r[0]; a1 = a1 + r[1]*r[1];
                a2 = a2 + r[2]*r[2]; a3 = a3 + r[3]*r[3];
                a4 = a4 + r[4]*r[4]; a5 = a5 + r[5]*r[5];
                a6 = a6 + r[6]*r[6]; a7 = a7 + r[7]*r[7];
            }
            blk[p] = ((a0 + a1) + (a2 + a3)) + ((a4 + a5) + (a6 + a7));
        }
        __syncthreads();
    }
    if (t < 64) dsq[row0 + t] = (blk[0] + blk[1]) + (blk[2] + blk[3]);
}

// ---------------- pass 1: bf16 MFMA GEMM + one-shot threshold + margin-append ----------------
// grid = 2048: blockIdx -> rowTile (bx>>4) x colChunk (bx&15, 512 cols each).
// Staging: XOR-16B-chunk swizzle (conflict-free, r2-proven).
// Epilogue v4: cross-lane min reduction ONLY at ct==0 (shfl chains + LDS atomicMin);
// thresholds then live in 16 VGPRs; ct1-3 test registers only (no barriers, no DS).
__global__ __launch_bounds__(256) void k_vq(const u16* __restrict__ A,   // [16384,512] bf16
                                            const u16* __restrict__ B,   // [8192,512] bf16
                                            const float* __restrict__ c2,
                                            u32* __restrict__ cnt,
                                            uint2* __restrict__ cand) {
    __shared__ u16 lAB[2 * 128 * 64];       // A tile | B tile (32 KiB)
    __shared__ u32 mrow[128];

    const int t    = threadIdx.x;
    const int wave = t >> 6, lane = t & 63;
    const int lr   = lane & 15, quad = lane >> 4;
    const int bx   = blockIdx.x;
    const int row0 = (bx >> 4) * 128;
    const int col0 = (bx & 15) * 512;
    const int wRow = (wave >> 1) * 64;
    const int wCol = (wave & 1) * 64;
    const int s0   = (quad ^ (lr & 7)) * 8;   // swizzled u16 chunk offset, kk=0

    if (t < 128) mrow[t] = 0xFFFFFFFFu;
    float thr[16];                            // per-(i,r) row threshold, set at ct==0

    for (int ct = 0; ct < 4; ct++) {
        const int colBase = col0 + ct * 128;
        f32x4 acc[4][4];
#pragma unroll
        for (int i = 0; i < 4; i++)
#pragma unroll
            for (int j = 0; j < 4; j++) { f32x4 z = {0.f, 0.f, 0.f, 0.f}; acc[i][j] = z; }

        for (int kb = 0; kb < DIM; kb += 64) {
#pragma unroll
            for (int p = 0; p < 4; p++) {
                int off = t * 16 + p * 4096;            // byte offset in 16 KiB tile
                int rr  = off >> 7;                     // tile row (128 B/row)
                int cc  = (off >> 4) & 7;               // LDS chunk position
                int sc  = (cc ^ (rr & 7)) << 3;         // source u16 col (XOR swizzle)
                const u16* ga = A + (size_t)(row0 + rr) * DIM + kb + sc;
                const u16* gb = B + (size_t)(colBase + rr) * DIM + kb + sc;
                __builtin_amdgcn_global_load_lds((const AS1 u32*)ga,
                                                 (AS3 u32*)((char*)lAB + off), 16, 0, 0);
                __builtin_amdgcn_global_load_lds((const AS1 u32*)gb,
                                                 (AS3 u32*)((char*)lAB + 16384 + off), 16, 0, 0);
            }
            __syncthreads();
#pragma unroll
            for (int kk = 0; kk < 2; kk++) {
                const int soff = s0 ^ (kk * 32);        // (chunk ^ 4kk)*8 in u16
                s16x8 af[4], bf[4];
#pragma unroll
                for (int i = 0; i < 4; i++)
                    af[i] = *(const s16x8*)&lAB[(wRow + i * 16 + lr) * 64 + soff];
#pragma unroll
                for (int j = 0; j < 4; j++)
                    bf[j] = *(const s16x8*)&lAB[8192 + (wCol + j * 16 + lr) * 64 + soff];
#pragma unroll
                for (int i = 0; i < 4; i++)
#pragma unroll
                    for (int j = 0; j < 4; j++)
                        acc[i][j] = __builtin_amdgcn_mfma_f32_16x16x32_bf16(af[i], bf[j], acc[i][j], 0, 0, 0);
            }
            __syncthreads();
        }

        float c2v[4];
#pragma unroll
        for (int j = 0; j < 4; j++) c2v[j] = c2[colBase + wCol + j * 16 + lr];

        if (ct == 0) {
            // one-shot row-min: shfl reduce over 16 col-lanes, merge col-halves via LDS atomicMin
#pragma unroll
            for (int i = 0; i < 4; i++) {
#pragma unroll
                for (int r = 0; r < 4; r++) {
                    float v0 = c2v[0] - 2.0f * acc[i][0][r];
                    float v1 = c2v[1] - 2.0f * acc[i][1][r];
                    float v2 = c2v[2] - 2.0f * acc[i][2][r];
                    float v3 = c2v[3] - 2.0f * acc[i][3][r];
                    float mn = fminf(fminf(v0, v1), fminf(v2, v3));
#pragma unroll
                    for (int mask = 1; mask < 16; mask <<= 1)
                        mn = fminf(mn, __shfl_xor(mn, mask));
                    if (lr == 0) atomicMin(&mrow[wRow + i * 16 + quad * 4 + r], encf(mn));
                }
            }
            __syncthreads();
#pragma unroll
            for (int i = 0; i < 4; i++)
#pragma unroll
                for (int r = 0; r < 4; r++)
                    thr[i * 4 + r] = decf(mrow[wRow + i * 16 + quad * 4 + r]) + MARGIN;
        }

        // margin-append (rare, divergent); registers-only thresholds
#pragma unroll
        for (int i = 0; i < 4; i++) {
#pragma unroll
            for (int r = 0; r < 4; r++) {
                const float th = thr[i * 4 + r];
                const int grow = row0 + wRow + i * 16 + quad * 4 + r;
#pragma unroll
                for (int j = 0; j < 4; j++) {
                    float s = c2v[j] - 2.0f * acc[i][j][r];
                    if (s < th) {
                        u32 idx = atomicAdd(&cnt[grow], 1u);
                        if (idx < CAP)
                            cand[(size_t)grow * CAP + idx] =
                                make_uint2(__float_as_uint(s), (u32)(colBase + wCol + j * 16 + lr));
                    }
                }
            }
        }
    }
}

// ---------------- pass 2: exact rescore (fp64 dot, np-fp32 pipeline) + gather + PE ----------------
__global__ __launch_bounds__(256) void k_fin(const float* __restrict__ x,
                                             const float* __restrict__ cb,
                                             const float* __restrict__ c2,
                                             const float* __restrict__ x2,
                                             const u32* __restrict__ cnt,
                                             const uint2* __restrict__ cand,
                                             float* __restrict__ out) {
    const int row  = (blockIdx.x * 256 + threadIdx.x) >> 6;   // one wave per row
    const int lane = threadIdx.x & 63;
    int n = (int)cnt[row];
    if (n > CAP) n = CAP;
    if (n < 0) n = 0;
    const uint2* cd = cand + (size_t)row * CAP;

    float m = 3.4028235e38f;
    for (int i = lane; i < n; i += 64) m = fminf(m, __uint_as_float(cd[i].x));
#pragma unroll
    for (int mask = 32; mask; mask >>= 1) m = fminf(m, __shfl_xor(m, mask));
    const float thr = m + RESCORE_MARGIN;

    const float* xr = x + (size_t)row * DIM + lane * 8;
    float4 xv0 = *(const float4*)xr;
    float4 xv1 = *(const float4*)(xr + 4);
    const float x2v = x2[row];

    u64 best = ~0ull;
    for (int i = 0; i < n; i++) {
        uint2 e = cd[i];
        float sa = __uint_as_float(e.x);
        u32 ci = (e.y < (u32)CODES) ? e.y : 0u;                // harden gather index
        if (sa <= thr) {                                       // wave-uniform branch
            const float* cr = cb + (size_t)ci * DIM + lane * 8;
            float4 c0 = *(const float4*)cr;
            float4 c1 = *(const float4*)(cr + 4);
            double d = (double)xv0.x * c0.x + (double)xv0.y * c0.y +
                       (double)xv0.z * c0.z + (double)xv0.w * c0.w +
                       (double)xv1.x * c1.x + (double)xv1.y * c1.y +
                       (double)xv1.z * c1.z + (double)xv1.w * c1.w;
#pragma unroll
            for (int mask = 32; mask; mask >>= 1) d += __shfl_xor(d, mask);
            float dot = (float)d;
            float s32 = (x2v - 2.0f * dot) + c2[ci];           // np fp32 pipeline
            u64 key = ((u64)encf(s32) << 32) | (u64)ci;        // lowest-index tie-break
            best = best < key ? best : key;
        }
    }
    u32 wcol = (u32)(best & 0xffffffffu);
    if (wcol >= (u32)CODES) wcol = 0;                          // unreachable safety

    const float* cw = cb + (size_t)wcol * DIM + lane * 8;
    float4 q0 = *(const float4*)cw;
    float4 q1 = *(const float4*)(cw + 4);
    const int spos = row & (SEQ - 1);
    float pe[8];
#pragma unroll
    for (int ii = 0; ii < 4; ii++) {
        int ipair = lane * 4 + ii;
        float dt  = expf((float)(2 * ipair) * (-0.017988946039035083f)); // ln(1e4)/512
        float ang = (float)spos * dt;
        float sv, cv;
        sincosf(ang, &sv, &cv);
        pe[2 * ii]     = sv;
        pe[2 * ii + 1] = cv;
    }
    float4* op = (float4*)(out + (size_t)row * DIM + lane * 8);
    op[0] = make_float4(q0.x + pe[0], q0.y + pe[1], q0.z + pe[2], q0.w + pe[3]);
    op[1] = make_float4(q1.x + pe[4], q1.y + pe[5], q1.z + pe[6], q1.w + pe[7]);
}

extern "C" void kernel_launch(void* const* d_in, const int* in_sizes, int n_in,
                              void* d_out, int out_size, void* d_ws, size_t ws_size,
                              hipStream_t stream) {
    const float* x  = (const float*)d_in[0];   // [8,2048,512]
    const float* cb = (const float*)d_in[1];   // [8192,512]
    float* out = (float*)d_out;

    char* ws = (char*)d_ws;
    u16*   Abf  = (u16*)ws;                                   // 16 MiB
    u16*   Bbf  = (u16*)(ws + 16777216);                      //  8 MiB
    float* c2   = (float*)(ws + 16777216 + 8388608);          // 32 KiB
    float* x2   = (float*)(ws + 16777216 + 8388608 + 32768);  // 64 KiB
    u32*   cnt  = (u32*)(ws + 16777216 + 8388608 + 32768 + 65536);            // 64 KiB
    uint2* cand = (uint2*)(ws + 16777216 + 8388608 + 32768 + 65536 + 65536);  // 16 MiB

    k_prep<<<dim3(384), dim3(256), 0, stream>>>(x, cb, Abf, Bbf, x2, c2, cnt);
    k_vq<<<dim3(2048), dim3(256), 0, stream>>>(Abf, Bbf, c2, cnt, cand);
    k_fin<<<dim3(4096), dim3(256), 0, stream>>>(x, cb, c2, x2, cnt, cand, out);
}

// Round 6
// 434.279 us; speedup vs baseline: 1.4830x; 1.1737x over previous
//
#include <hip/hip_runtime.h>
#include <stdint.h>

typedef unsigned int       u32;
typedef unsigned long long u64;
typedef unsigned short     u16;

typedef float f32x4 __attribute__((ext_vector_type(4)));
typedef short s16x8 __attribute__((ext_vector_type(8)));

#define AS1 __attribute__((address_space(1)))
#define AS3 __attribute__((address_space(3)))

constexpr int BATCH = 8, SEQ = 2048, DIM = 512, CODES = 8192;
constexpr int MROWS = BATCH * SEQ;          // 16384
constexpr int CAP   = 128;                  // candidate slots per row
#define MARGIN          1.0f                // append margin (~16 sigma of bf16 dot err)
#define RESCORE_MARGIN  0.6f                // exact-rescore filter (~8 sigma)

// ---- ordered-uint encode for float min ----
__device__ __forceinline__ u32 encf(float f) {
    u32 u = __float_as_uint(f);
    return (u & 0x80000000u) ? ~u : (u | 0x80000000u);
}
__device__ __forceinline__ float decf(u32 e) {
    return (e & 0x80000000u) ? __uint_as_float(e & 0x7fffffffu) : __uint_as_float(~e);
}
__device__ __forceinline__ u16 f2bf(float f) {           // RTNE, finite inputs
    u32 u = __float_as_uint(f);
    return (u16)((u + 0x7fffu + ((u >> 16) & 1u)) >> 16);
}

// ---------------- pass 0: fused fp32->bf16 cast + numpy-pairwise-exact row sumsq ----------------
__global__ __launch_bounds__(256) void k_prep(const float* __restrict__ x,
                                              const float* __restrict__ cb,
                                              u16* __restrict__ dx,
                                              u16* __restrict__ dcb,
                                              float* __restrict__ x2,
                                              float* __restrict__ c2,
                                              u32* __restrict__ cnt) {
#pragma clang fp contract(off)
    __shared__ float lp[64 * 133];
    const int t  = threadIdx.x;
    const int bx = blockIdx.x;
    const int gid = bx * 256 + t;
    if (gid < MROWS) cnt[gid] = 0u;

    const float* src; u16* dst; float* dsq; int row0;
    if (bx < 256) { src = x;  dst = dx;  dsq = x2; row0 = bx * 64; }
    else          { src = cb; dst = dcb; dsq = c2; row0 = (bx - 256) * 64; }

    float blk[4];
    for (int p = 0; p < 4; p++) {
#pragma unroll
        for (int k = 0; k < 8; k++) {
            int idx = t + 256 * k;
            int row = idx >> 5, c4 = idx & 31;
            const float* gp = src + (size_t)(row0 + row) * DIM + p * 128 + c4 * 4;
            float4 v = *(const float4*)gp;
            u64 pk = (u64)f2bf(v.x) | ((u64)f2bf(v.y) << 16) |
                     ((u64)f2bf(v.z) << 32) | ((u64)f2bf(v.w) << 48);
            *(u64*)(dst + (size_t)(row0 + row) * DIM + p * 128 + c4 * 4) = pk;
            int la = row * 133 + c4 * 4;
            lp[la] = v.x; lp[la + 1] = v.y; lp[la + 2] = v.z; lp[la + 3] = v.w;
        }
        __syncthreads();
        if (t < 64) {
            const float* q = lp + t * 133;
            float a0 = q[0]*q[0], a1 = q[1]*q[1], a2 = q[2]*q[2], a3 = q[3]*q[3];
            float a4 = q[4]*q[4], a5 = q[5]*q[5], a6 = q[6]*q[6], a7 = q[7]*q[7];
            for (int i = 1; i < 16; i++) {
                const float* r = q + i * 8;
                a0 = a0 + r[0]*r[0]; a1 = a1 + r[1]*r[1];
                a2 = a2 + r[2]*r[2]; a3 = a3 + r[3]*r[3];
                a4 = a4 + r[4]*r[4]; a5 = a5 + r[5]*r[5];
                a6 = a6 + r[6]*r[6]; a7 = a7 + r[7]*r[7];
            }
            blk[p] = ((a0 + a1) + (a2 + a3)) + ((a4 + a5) + (a6 + a7));
        }
        __syncthreads();
    }
    if (t < 64) dsq[row0 + t] = (blk[0] + blk[1]) + (blk[2] + blk[3]);
}

// ---------------- pass 1: 256x256-tile bf16 MFMA GEMM, dbuf prefetch-across-barrier ----------------
// grid = 2048 = 64 row-tiles x 32 col-tiles; block = 512 threads (8 waves).
// Wave = 128 rows x 64 cols (acc 8x4 frags). K-loop = 8 iters of BK=64, LDS double-
// buffered (2 x (A 32K | B 32K)); loads for iter n+1 are issued AFTER the barrier
// that opens iter n, so the vmcnt(0)-before-barrier only sees ~1-compute-phase-old
// loads (drain ~0). XOR-16B-chunk swizzle keeps ds_read_b128 conflict-free.
__global__ __launch_bounds__(512, 2) void k_vq(const u16* __restrict__ A,   // [16384,512] bf16
                                               const u16* __restrict__ B,   // [8192,512] bf16
                                               const float* __restrict__ c2,
                                               u32* __restrict__ cnt,
                                               uint2* __restrict__ cand) {
    __shared__ u16 lds[2 * 32768];          // [buf][A 16K u16 | B 16K u16] = 128 KiB
    __shared__ u32 mrow[256];

    const int t    = threadIdx.x;
    const int wave = t >> 6, lane = t & 63;
    const int lr   = lane & 15, quad = lane >> 4;
    const int bx   = blockIdx.x;
    const int row0 = (bx & 63) * 256;
    const int col0 = (bx >> 6) * 256;
    const int wRow = (wave >> 2) * 128;     // 2 row-bands
    const int wCol = (wave & 3) * 64;       // 4 col-bands
    const int s0   = (quad ^ (lr & 7)) * 8; // swizzled u16 chunk offset, kk=0

    if (t < 256) mrow[t] = 0xFFFFFFFFu;

    f32x4 acc[8][4];
#pragma unroll
    for (int i = 0; i < 8; i++)
#pragma unroll
        for (int j = 0; j < 4; j++) { f32x4 z = {0.f, 0.f, 0.f, 0.f}; acc[i][j] = z; }

    // ---- staging helper (macro-style lambda): issue 8 global_load_lds for (it, buf) ----
    auto stage = [&](int it, int buf) {
        const int kb = it * 64;
#pragma unroll
        for (int p = 0; p < 4; p++) {
            int off = t * 16 + p * 8192;            // byte offset within 32 KiB tile
            int rr  = off >> 7;                     // tile row (128 B/row), 0..255
            int cc  = (off >> 4) & 7;               // LDS chunk position
            int sc  = (cc ^ (rr & 7)) << 3;         // source u16 col (XOR swizzle)
            const u16* ga = A + (size_t)(row0 + rr) * DIM + kb + sc;
            const u16* gb = B + (size_t)(col0 + rr) * DIM + kb + sc;
            __builtin_amdgcn_global_load_lds((const AS1 u32*)ga,
                                             (AS3 u32*)((char*)lds + buf * 65536 + off), 16, 0, 0);
            __builtin_amdgcn_global_load_lds((const AS1 u32*)gb,
                                             (AS3 u32*)((char*)lds + buf * 65536 + 32768 + off), 16, 0, 0);
        }
    };

    stage(0, 0);                              // preamble prefetch
    for (int it = 0; it < 8; it++) {
        const int buf = it & 1;
        __syncthreads();                      // drains buf's loads (issued 1 compute-phase ago)
        if (it < 7) stage(it + 1, buf ^ 1);   // prefetch next AFTER the barrier
        const u16* bufA = lds + buf * 32768;
        const u16* bufB = bufA + 16384;
#pragma unroll
        for (int kk = 0; kk < 2; kk++) {
            const int soff = s0 ^ (kk * 32);  // (chunk ^ 4kk)*8 in u16
            s16x8 af[8], bf[4];
#pragma unroll
            for (int i = 0; i < 8; i++)
                af[i] = *(const s16x8*)&bufA[(wRow + i * 16 + lr) * 64 + soff];
#pragma unroll
            for (int j = 0; j < 4; j++)
                bf[j] = *(const s16x8*)&bufB[(wCol + j * 16 + lr) * 64 + soff];
#pragma unroll
            for (int i = 0; i < 8; i++)
#pragma unroll
                for (int j = 0; j < 4; j++)
                    acc[i][j] = __builtin_amdgcn_mfma_f32_16x16x32_bf16(af[i], bf[j], acc[i][j], 0, 0, 0);
        }
    }

    // ---- epilogue: row-min over this block's 256 cols -> threshold -> margin-append ----
    float c2v[4];
#pragma unroll
    for (int j = 0; j < 4; j++) c2v[j] = c2[col0 + wCol + j * 16 + lr];

#pragma unroll
    for (int i = 0; i < 8; i++) {
#pragma unroll
        for (int r = 0; r < 4; r++) {
            float v0 = c2v[0] - 2.0f * acc[i][0][r];
            float v1 = c2v[1] - 2.0f * acc[i][1][r];
            float v2 = c2v[2] - 2.0f * acc[i][2][r];
            float v3 = c2v[3] - 2.0f * acc[i][3][r];
            float mn = fminf(fminf(v0, v1), fminf(v2, v3));
#pragma unroll
            for (int mask = 1; mask < 16; mask <<= 1)
                mn = fminf(mn, __shfl_xor(mn, mask));
            if (lr == 0) atomicMin(&mrow[wRow + i * 16 + quad * 4 + r], encf(mn));
        }
    }
    __syncthreads();
#pragma unroll
    for (int i = 0; i < 8; i++) {
#pragma unroll
        for (int r = 0; r < 4; r++) {
            const int lrow = wRow + i * 16 + quad * 4 + r;
            const float th = decf(mrow[lrow]) + MARGIN;
            const int grow = row0 + lrow;
#pragma unroll
            for (int j = 0; j < 4; j++) {
                float s = c2v[j] - 2.0f * acc[i][j][r];
                if (s < th) {
                    u32 idx = atomicAdd(&cnt[grow], 1u);
                    if (idx < CAP)
                        cand[(size_t)grow * CAP + idx] =
                            make_uint2(__float_as_uint(s), (u32)(col0 + wCol + j * 16 + lr));
                }
            }
        }
    }
}

// ---------------- pass 2: exact rescore (fp64 dot, np-fp32 pipeline) + gather + PE ----------------
__global__ __launch_bounds__(256) void k_fin(const float* __restrict__ x,
                                             const float* __restrict__ cb,
                                             const float* __restrict__ c2,
                                             const float* __restrict__ x2,
                                             const u32* __restrict__ cnt,
                                             const uint2* __restrict__ cand,
                                             float* __restrict__ out) {
    const int row  = (blockIdx.x * 256 + threadIdx.x) >> 6;   // one wave per row
    const int lane = threadIdx.x & 63;
    int n = (int)cnt[row];
    if (n > CAP) n = CAP;
    if (n < 0) n = 0;
    const uint2* cd = cand + (size_t)row * CAP;

    float m = 3.4028235e38f;
    for (int i = lane; i < n; i += 64) m = fminf(m, __uint_as_float(cd[i].x));
#pragma unroll
    for (int mask = 32; mask; mask >>= 1) m = fminf(m, __shfl_xor(m, mask));
    const float thr = m + RESCORE_MARGIN;

    const float* xr = x + (size_t)row * DIM + lane * 8;
    float4 xv0 = *(const float4*)xr;
    float4 xv1 = *(const float4*)(xr + 4);
    const float x2v = x2[row];

    u64 best = ~0ull;
    for (int i = 0; i < n; i++) {
        uint2 e = cd[i];
        float sa = __uint_as_float(e.x);
        u32 ci = (e.y < (u32)CODES) ? e.y : 0u;                // harden gather index
        if (sa <= thr) {                                       // wave-uniform branch
            const float* cr = cb + (size_t)ci * DIM + lane * 8;
            float4 c0 = *(const float4*)cr;
            float4 c1 = *(const float4*)(cr + 4);
            double d = (double)xv0.x * c0.x + (double)xv0.y * c0.y +
                       (double)xv0.z * c0.z + (double)xv0.w * c0.w +
                       (double)xv1.x * c1.x + (double)xv1.y * c1.y +
                       (double)xv1.z * c1.z + (double)xv1.w * c1.w;
#pragma unroll
            for (int mask = 32; mask; mask >>= 1) d += __shfl_xor(d, mask);
            float dot = (float)d;
            float s32 = (x2v - 2.0f * dot) + c2[ci];           // np fp32 pipeline
            u64 key = ((u64)encf(s32) << 32) | (u64)ci;        // lowest-index tie-break
            best = best < key ? best : key;
        }
    }
    u32 wcol = (u32)(best & 0xffffffffu);
    if (wcol >= (u32)CODES) wcol = 0;                          // unreachable safety

    const float* cw = cb + (size_t)wcol * DIM + lane * 8;
    float4 q0 = *(const float4*)cw;
    float4 q1 = *(const float4*)(cw + 4);
    const int spos = row & (SEQ - 1);
    float pe[8];
#pragma unroll
    for (int ii = 0; ii < 4; ii++) {
        int ipair = lane * 4 + ii;
        float dt  = expf((float)(2 * ipair) * (-0.017988946039035083f)); // ln(1e4)/512
        float ang = (float)spos * dt;
        float sv, cv;
        sincosf(ang, &sv, &cv);
        pe[2 * ii]     = sv;
        pe[2 * ii + 1] = cv;
    }
    float4* op = (float4*)(out + (size_t)row * DIM + lane * 8);
    op[0] = make_float4(q0.x + pe[0], q0.y + pe[1], q0.z + pe[2], q0.w + pe[3]);
    op[1] = make_float4(q1.x + pe[4], q1.y + pe[5], q1.z + pe[6], q1.w + pe[7]);
}

extern "C" void kernel_launch(void* const* d_in, const int* in_sizes, int n_in,
                              void* d_out, int out_size, void* d_ws, size_t ws_size,
                              hipStream_t stream) {
    const float* x  = (const float*)d_in[0];   // [8,2048,512]
    const float* cb = (const float*)d_in[1];   // [8192,512]
    float* out = (float*)d_out;

    char* ws = (char*)d_ws;
    u16*   Abf  = (u16*)ws;                                   // 16 MiB
    u16*   Bbf  = (u16*)(ws + 16777216);                      //  8 MiB
    float* c2   = (float*)(ws + 16777216 + 8388608);          // 32 KiB
    float* x2   = (float*)(ws + 16777216 + 8388608 + 32768);  // 64 KiB
    u32*   cnt  = (u32*)(ws + 16777216 + 8388608 + 32768 + 65536);            // 64 KiB
    uint2* cand = (uint2*)(ws + 16777216 + 8388608 + 32768 + 65536 + 65536);  // 16 MiB

    k_prep<<<dim3(384), dim3(256), 0, stream>>>(x, cb, Abf, Bbf, x2, c2, cnt);
    k_vq<<<dim3(2048), dim3(512), 0, stream>>>(Abf, Bbf, c2, cnt, cand);
    k_fin<<<dim3(4096), dim3(256), 0, stream>>>(x, cb, c2, x2, cnt, cand, out);
}